// Round 4
// baseline (126.563 us; speedup 1.0000x reference)
//
#include <hip/hip_runtime.h>

// ---------------------------------------------------------------------------
// LaplaceKAN as fused-feature bf16 MFMA GEMM. M=4096, N=256, K=8192
// (k = s*4096 + i*16 + g), A = exp(sgn*x*lam_g) generated in-kernel,
// B = coeffs pre-cast to bf16 (natural [o][k] B^T layout).
// R4 change: NO split-K, NO reduce kernel. R1-R3 showed dur_us insensitive to
// GEMM occupancy (8 vs 16 waves/CU identical) -> timed window is dominated by
// harness fills/restores + dispatch gaps + kernel memory traffic. So: 2
// dispatches total (convert, gemm), epilogue writes Out+bias directly
// (4 MB instead of 32 MB P + 33 MB re-read + reduce kernel + node gap).
// Grid (128,4)=512 blocks, BM=32/BN=64/BK=128, 64 j-iters, sign flip at j=32.
// ---------------------------------------------------------------------------

typedef __bf16 bf16x8 __attribute__((ext_vector_type(8)));
typedef __bf16 bf16x4 __attribute__((ext_vector_type(4)));
typedef float  f32x4  __attribute__((ext_vector_type(4)));

#define M_TOT 4096
#define N_TOT 256

__device__ __forceinline__ void gload_lds16(const __bf16* g, __bf16* l) {
  // async 16B/lane global->LDS; LDS dest = wave-uniform base + lane*16
  __builtin_amdgcn_global_load_lds(
      (const __attribute__((address_space(1))) void*)g,
      (__attribute__((address_space(3))) void*)l, 16, 0, 0);
}

// fp32 coeffs (2,O,I,G) -> bf16 Wb[o][k], k = s*4096 + i*16 + g.
__global__ void convert_w(const float* __restrict__ C, __bf16* __restrict__ W) {
  int t = blockIdx.x * 256 + threadIdx.x;      // 524288 threads, 4 elems each
  int E = t << 2;
  int c = E >> 12, x4 = E & 4095;              // c = s*256+o
  int s = c >> 8, o = c & 255;
  const f32x4 v = *(const f32x4*)(C + (size_t)c * 4096 + x4);
  bf16x4 w;
  w[0] = (__bf16)v[0]; w[1] = (__bf16)v[1]; w[2] = (__bf16)v[2]; w[3] = (__bf16)v[3];
  *(bf16x4*)(W + (size_t)o * 8192 + (size_t)s * 4096 + x4) = w;
}

__global__ __launch_bounds__(256, 4)
void laplace_gemm(const float* __restrict__ X, const __bf16* __restrict__ Wb,
                  const float* __restrict__ Bias, float* __restrict__ Out) {
  // B tile 64 n-rows x 128 k (16 KB); 16B chunks XOR-swizzled by (row&15)
  __shared__ __bf16 Bs[64 * 128];
  // A tile 32 m-rows x 128 k, row stride 136 (272B, bank-staggered) = 8.5 KB
  __shared__ __bf16 As[32 * 136];

  const int tid = threadIdx.x;                 // 256 threads = 4 waves
  const int m0 = blockIdx.x * 32, n0 = blockIdx.y * 64;

  const int wv = tid >> 6, lane = tid & 63;
  const int wm = wv & 1, wn = wv >> 1;         // 2x2 wave grid; wave = 16m x 32n
  const int lm = lane & 15, q = lane >> 4;

  // A-gen: each thread owns one (row, i-sub) pair: all 16 g's of it per j
  const int row = tid >> 3, di = tid & 7;      // row 0..31, di 0..7
  const float* xrowp = X + (size_t)(m0 + row) * 256 + di;   // i = jj*8 + di

  const f32x4 zero = {0.f, 0.f, 0.f, 0.f};
  f32x4 acc[2] = {zero, zero};

  float xc = xrowp[0];                         // j=0: jj=0

  for (int j = 0; j < 64; ++j) {               // 64 x BK=128 = K 8192
    const int jj = j & 31, s = j >> 5;         // sign half: s=0 -> exp(-e)
    const size_t kb = (size_t)s * 4096 + (size_t)jj * 128;

    // ---- async stage B tile: 1024 chunks of 16B / 256 threads = 4 each ----
#pragma unroll
    for (int qq = 0; qq < 4; ++qq) {
      const int idx = qq * 256 + tid;
      const int r = idx >> 4, cc = idx & 15;
      const __bf16* gsrc = Wb + (size_t)(n0 + r) * 8192 + kb + ((cc ^ (r & 15)) << 3);
      __bf16* ldst = Bs + ((qq * 256 + (tid & ~63)) << 3);  // wave-uniform base
      gload_lds16(gsrc, ldst);
    }

    // prefetch next iter's x while loads are in flight
    float xn = 0.f;
    if (j < 63) xn = xrowp[((j + 1) & 31) * 8];

    // ---- generate A features: f_g = p * r^g, two independent 8-chains ----
    {
      const float sgn = s ? 1.0f : -1.0f;
      const float p = __expf(0.1f * sgn * xc), r = __expf(0.06f * sgn * xc);
      const float r2 = r * r, r4 = r2 * r2, r8 = r4 * r4;
      bf16x8 v0, v1; float f = p, f2 = p * r8;
#pragma unroll
      for (int h = 0; h < 8; ++h) { v0[h] = (__bf16)f;  f  *= r; }
#pragma unroll
      for (int h = 0; h < 8; ++h) { v1[h] = (__bf16)f2; f2 *= r; }
      *(bf16x8*)&As[row * 136 + di * 16]     = v0;
      *(bf16x8*)&As[row * 136 + di * 16 + 8] = v1;
    }

    __syncthreads();   // drains vmcnt (B tile) + lgkm (A writes)

    // ---- MFMA: 4 k-steps x 1x2 frags (per-wave 16m x 32n) ----
#pragma unroll
    for (int kk = 0; kk < 4; ++kk) {
      bf16x8 af = *(const bf16x8*)&As[(wm * 16 + lm) * 136 + kk * 32 + q * 8];
      const int pc = ((kk << 2) + q) ^ lm;     // un-swizzle B chunk
#pragma unroll
      for (int b = 0; b < 2; ++b) {
        bf16x8 bfr = *(const bf16x8*)&Bs[(wn * 32 + b * 16 + lm) * 128 + (pc << 3)];
        acc[b] = __builtin_amdgcn_mfma_f32_16x16x32_bf16(af, bfr, acc[b], 0, 0, 0);
      }
    }
    __syncthreads();   // before next iter overwrites tiles

    xc = xn;
  }

  // ---- epilogue: D[row=q*4+reg][col=lm], direct Out write + bias ----
#pragma unroll
  for (int b = 0; b < 2; ++b) {
    const int n = n0 + wn * 32 + b * 16 + lm;
    const float bias = Bias[n];
    const int mrow = m0 + wm * 16 + q * 4;
#pragma unroll
    for (int rr = 0; rr < 4; ++rr)
      Out[(size_t)(mrow + rr) * 256 + n] = acc[b][rr] + bias;
  }
}

extern "C" void kernel_launch(void* const* d_in, const int* in_sizes, int n_in,
                              void* d_out, int out_size, void* d_ws, size_t ws_size,
                              hipStream_t stream) {
  const float* X    = (const float*)d_in[0];
  const float* C    = (const float*)d_in[1];
  const float* Bias = (const float*)d_in[2];
  float* Out = (float*)d_out;

  __bf16* Wb = (__bf16*)d_ws;                  // 4 MiB of workspace

  convert_w<<<2048, 256, 0, stream>>>(C, Wb);
  laplace_gemm<<<dim3(128, 4), 256, 0, stream>>>(X, Wb, Bias, Out);
}

// Round 5
// 118.934 us; speedup vs baseline: 1.0641x; 1.0641x over previous
//
#include <hip/hip_runtime.h>

// ---------------------------------------------------------------------------
// LaplaceKAN as fused-feature bf16 MFMA GEMM. M=4096, N=256, K=8192
// (k = s*4096 + i*16 + g), y = A(x)·W^T + bias with A generated on the fly.
// R5: ZERO-LDS, ZERO-BARRIER GEMM. R4 counters (MfmaUtil 9.5%, 4.19M LDS bank
// conflicts, 128 barrier-pairs) showed the LDS-staged structure is barrier/
// conflict-bound. Now both MFMA operands live in registers:
//   A-frag: lane (lm,q) computes exp(sgn*x[m,i0+(q>>1)]*lam_g), g=(q&1)*8..+7
//           via p*r^g recurrence -> direct into A-operand VGPRs. No LDS.
//   B-frag: global_load_dwordx4 straight from L2-resident Wb (4 MB), double-
//           buffered one step ahead. L2 B-traffic = (M/64)*4MB = 256 MB.
// Wave = 64m x 128n x 1024k: acc 4x8 frags (128 VGPR) ~250 VGPR total,
// 1 wave/SIMD (launch_bounds(128,1) -> 512 VGPR budget).
// Grid 64 mt x SPLITK 8 = 512 two-wave blocks = 4 waves/CU, every SIMD fed.
// K-loop has NO __syncthreads -- only compiler vmcnt waits on prefetched B.
// ---------------------------------------------------------------------------

typedef __bf16 bf16x8 __attribute__((ext_vector_type(8)));
typedef __bf16 bf16x4 __attribute__((ext_vector_type(4)));
typedef float  f32x4  __attribute__((ext_vector_type(4)));

#define M_TOT 4096
#define N_TOT 256
#define MN_TOT (M_TOT * N_TOT)
#define SPLITK 8

// fp32 coeffs (2,O,I,G) -> bf16 Wb[o][k], k = s*4096 + i*16 + g.
__global__ void convert_w(const float* __restrict__ C, __bf16* __restrict__ W) {
  int t = blockIdx.x * 256 + threadIdx.x;      // 524288 threads, 4 elems each
  int E = t << 2;
  int c = E >> 12, x4 = E & 4095;              // c = s*256+o
  int s = c >> 8, o = c & 255;
  const f32x4 v = *(const f32x4*)(C + (size_t)c * 4096 + x4);
  bf16x4 w;
  w[0] = (__bf16)v[0]; w[1] = (__bf16)v[1]; w[2] = (__bf16)v[2]; w[3] = (__bf16)v[3];
  *(bf16x4*)(W + (size_t)o * 8192 + (size_t)s * 4096 + x4) = w;
}

// MODE 0: write split-K partials to P.  MODE 1: atomicAdd into Out (+bias at ks==0).
template <int MODE>
__global__ __launch_bounds__(128, 1)
void laplace_gemm(const float* __restrict__ X, const __bf16* __restrict__ Wb,
                  const float* __restrict__ Bias, float* __restrict__ Out,
                  float* __restrict__ P) {
  const int tid = threadIdx.x;                 // 128 threads = 2 waves (n-halves)
  const int mt = blockIdx.x, ks = blockIdx.y;  // 64 m-tiles x 8 k-chunks
  const int w = tid >> 6, lane = tid & 63;
  const int lm = lane & 15, q = lane >> 4;

  const int s = ks >> 2;                       // sign: 0 -> exp(-e), 1 -> exp(+e)
  const int ibase = (ks & 3) * 64 + (q >> 1);  // lane's first i of this k-chunk
  const float sgn = s ? 1.0f : -1.0f;
  const float c0 = 0.1f * sgn, cd = 0.06f * sgn;
  const bool qodd = (q & 1) != 0;              // lane covers g=8..15 of its i

  // x row pointers for the 4 m-frags (row = mt*64 + a*16 + lm)
  const float* xr0 = X + (size_t)(mt * 64 +  0 + lm) * 256 + ibase;
  const float* xr1 = X + (size_t)(mt * 64 + 16 + lm) * 256 + ibase;
  const float* xr2 = X + (size_t)(mt * 64 + 32 + lm) * 256 + ibase;
  const float* xr3 = X + (size_t)(mt * 64 + 48 + lm) * 256 + ibase;

  // B base: lane's n-row = w*128 + lm (+b*16 via 131072-elem stride), k = ks*1024 + j*32 + q*8
  const __bf16* bb = Wb + (size_t)(w * 128 + lm) * 8192 + ks * 1024 + q * 8;

  const f32x4 zero = {0.f, 0.f, 0.f, 0.f};
  f32x4 acc[4][8];
#pragma unroll
  for (int a = 0; a < 4; ++a)
#pragma unroll
    for (int b = 0; b < 8; ++b) acc[a][b] = zero;

  bf16x8 Bf[2][8];
  float  xv[2][4];

  // preload step 0
#pragma unroll
  for (int b = 0; b < 8; ++b)
    Bf[0][b] = *(const bf16x8*)(bb + (size_t)b * 131072);
  xv[0][0] = xr0[0]; xv[0][1] = xr1[0]; xv[0][2] = xr2[0]; xv[0][3] = xr3[0];

#pragma unroll 2
  for (int j = 0; j < 32; ++j) {               // 32 steps x 32k = 1024 k
    const int cur = j & 1, nxt = cur ^ 1;
    const int jn = (j < 31) ? (j + 1) : 0;     // wrap keeps prefetch in-bounds

    // ---- prefetch next step's B frags + x (in flight during MFMAs below) ----
#pragma unroll
    for (int b = 0; b < 8; ++b)
      Bf[nxt][b] = *(const bf16x8*)(bb + (size_t)b * 131072 + jn * 32);
    xv[nxt][0] = xr0[2 * jn]; xv[nxt][1] = xr1[2 * jn];
    xv[nxt][2] = xr2[2 * jn]; xv[nxt][3] = xr3[2 * jn];

    // ---- generate A frags in registers: f_g = p * r^g ----
    bf16x8 Af[4];
#pragma unroll
    for (int a = 0; a < 4; ++a) {
      const float x = xv[cur][a];
      const float p = __expf(c0 * x), r = __expf(cd * x);
      const float r2 = r * r, r4 = r2 * r2, r8 = r4 * r4;
      float f = qodd ? p * r8 : p;             // per-lane cndmask, no branch
#pragma unroll
      for (int h = 0; h < 8; ++h) { Af[a][h] = (__bf16)f; f *= r; }
    }

    // ---- 32 MFMAs, no barriers ----
#pragma unroll
    for (int a = 0; a < 4; ++a)
#pragma unroll
      for (int b = 0; b < 8; ++b)
        acc[a][b] = __builtin_amdgcn_mfma_f32_16x16x32_bf16(Af[a], Bf[cur][b], acc[a][b], 0, 0, 0);
  }

  // ---- epilogue: D[row=q*4+rr][col=lm] (m89-verified C/D layout) ----
  if constexpr (MODE == 0) {
    float* Pk = P + (size_t)ks * MN_TOT + (size_t)w * 128;
#pragma unroll
    for (int a = 0; a < 4; ++a)
#pragma unroll
      for (int rr = 0; rr < 4; ++rr) {
        const int mrow = mt * 64 + a * 16 + q * 4 + rr;
#pragma unroll
        for (int b = 0; b < 8; ++b)
          Pk[(size_t)mrow * 256 + b * 16 + lm] = acc[a][b][rr];
      }
  } else {
#pragma unroll
    for (int a = 0; a < 4; ++a)
#pragma unroll
      for (int rr = 0; rr < 4; ++rr) {
        const int mrow = mt * 64 + a * 16 + q * 4 + rr;
#pragma unroll
        for (int b = 0; b < 8; ++b) {
          const int n = w * 128 + b * 16 + lm;
          float v = acc[a][b][rr];
          if (ks == 0) v += Bias[n];
          atomicAdd(&Out[(size_t)mrow * 256 + n], v);
        }
      }
  }
}

// sum 8 split-K partials + bias -> out
__global__ void reduce_bias(const float* __restrict__ P, const float* __restrict__ Bias,
                            float* __restrict__ Out) {
  const int t = blockIdx.x * 256 + threadIdx.x;
  const size_t base = (size_t)t * 4;
  f32x4 sv = *(const f32x4*)&P[base];
#pragma unroll
  for (int k = 1; k < SPLITK; ++k) sv += *(const f32x4*)&P[(size_t)k * MN_TOT + base];
  sv += *(const f32x4*)&Bias[base & 255];
  *(f32x4*)&Out[base] = sv;
}

extern "C" void kernel_launch(void* const* d_in, const int* in_sizes, int n_in,
                              void* d_out, int out_size, void* d_ws, size_t ws_size,
                              hipStream_t stream) {
  const float* X    = (const float*)d_in[0];
  const float* C    = (const float*)d_in[1];
  const float* Bias = (const float*)d_in[2];
  float* Out = (float*)d_out;

  __bf16* Wb = (__bf16*)d_ws;
  const size_t wb_bytes = (size_t)N_TOT * 8192 * sizeof(__bf16);   // 4 MiB
  const size_t p_bytes  = (size_t)SPLITK * MN_TOT * sizeof(float); // 32 MiB
  float* P = (float*)((char*)d_ws + wb_bytes);

  convert_w<<<2048, 256, 0, stream>>>(C, Wb);

  if (ws_size >= wb_bytes + p_bytes) {
    laplace_gemm<0><<<dim3(64, SPLITK), 128, 0, stream>>>(X, Wb, Bias, Out, P);
    reduce_bias<<<1024, 256, 0, stream>>>(P, Bias, Out);
  } else {
    hipMemsetAsync(d_out, 0, (size_t)out_size * sizeof(float), stream);
    laplace_gemm<1><<<dim3(64, SPLITK), 128, 0, stream>>>(X, Wb, Bias, Out, P);
  }
}